// Round 11
// baseline (409.752 us; speedup 1.0000x reference)
//
#include <hip/hip_runtime.h>
#include <hip/hip_bf16.h>
#include <math.h>

#define NPTS 8192
#define STAT_CNT 262144.0f
#define BN_EPS 1e-5f

typedef __attribute__((__ext_vector_type__(8))) __bf16 bf16x8;
typedef __attribute__((__ext_vector_type__(4))) float f32x4;

// stats region float offsets
#define SD_SUM 0
#define SD_SSQ 4
#define SD_SC 8
#define SD_SH 12
#define SG1_SC 16
#define SG1_SH 144
#define SG2_SC 272
#define SG2_SH 400
#define PG1 528
#define PG2 8720
#define STATS_FLOATS 16912

__device__ __forceinline__ unsigned short f2b(float x){
  unsigned u = __float_as_uint(x);
  return (unsigned short)((u + 0x7FFFu + ((u>>16)&1u)) >> 16);
}
__device__ __forceinline__ float b2f(unsigned short h){
  return __uint_as_float(((unsigned)h)<<16);
}
// gelu with A&S 7.1.26 erf approx: |err| <= 1.5e-7 absolute (4 orders below
// bf16 storage rounding), ~12 VALU ops with HW v_exp vs ~30+ for libm erff.
// R10 lesson: erff was the bulk of k_g/k_out's 39% VALUBusy.
__device__ __forceinline__ float gelu_f(float x){
  float u = fabsf(x)*0.70710678118654752440f;
  float t = 1.0f/fmaf(0.3275911f, u, 1.0f);
  float p = t*fmaf(t,fmaf(t,fmaf(t,fmaf(t,1.061405429f,-1.453152027f),1.421413741f),-0.284496736f),0.254829592f);
  float er = fmaf(-p, __expf(-u*u), 1.0f);
  er = (x < 0.f) ? -er : er;
  return 0.5f*x*(1.0f+er);
}
// XOR-swizzled LDS addressing for [rows][256B] bf16 tiles (G4 fix)
__device__ __forceinline__ int swz(int row, int byteInRow){
  return row*256 + (byteInRow ^ ((row&7)<<4));
}
// distance formula shared by both kNN phases: MUST be one inline so phase-1
// and phase-2 roundings are bit-identical (d <= t is exact multiset membership)
__device__ __forceinline__ float dist2f(float qx,float qy,float qz,float qpn,
                                        float x,float y,float z,float w){
  return (qpn + w) - 2.0f*fmaf(qx,x,fmaf(qy,y,qz*z));
}

#define MFMA16(a,b,c) __builtin_amdgcn_mfma_f32_16x16x32_bf16((a),(b),(c),0,0,0)

__device__ __forceinline__ bf16x8 ldsA8(const unsigned short* sA, int row, int k){
  return *(const bf16x8*)((const char*)sA + swz(row, k*2));
}
__device__ __forceinline__ bf16x8 ldW8(const unsigned short* W, int n, int k){
  return *(const bf16x8*)(W + n*128 + k);
}

__global__ __launch_bounds__(256) void k_prep(
    const float* __restrict__ feats, const float* __restrict__ Wq, const float* __restrict__ Wk,
    const float* __restrict__ Wv, const float* __restrict__ Wg1, const float* __restrict__ Wg2,
    unsigned short* __restrict__ wbf, unsigned short* __restrict__ featb, float* __restrict__ stats)
{
  int i = blockIdx.x*256 + threadIdx.x;   // grid covers exactly 2097152
  featb[i] = f2b(feats[i]);
  if (i < 16384){
    wbf[i]        = f2b(Wq[i]);
    wbf[16384+i]  = f2b(Wk[i]);
    wbf[32768+i]  = f2b(Wv[i]);
    wbf[49152+i]  = f2b(Wg1[i]);
    wbf[65536+i]  = f2b(Wg2[i]);
  }
  if (i < STATS_FLOATS) stats[i] = 0.f;
}

// barrier-free threshold-filter kNN, 4 queries/wave, candidates read DIRECTLY
// from global (96KB/batch = L2-resident). Survivor buffers wave-private.
// Selection = rank-by-count over ~18 survivors (ranks unique, lex-(d,idx)).
__global__ __launch_bounds__(256) void k_knn5(const float* __restrict__ points, int* __restrict__ idxb){
  __shared__ float svD[16][64];
  __shared__ int   svI[16][64];
  __shared__ int   svC[16];
  int tid = threadIdx.x;
  int wid = tid>>6, lane = tid&63;
  int blk = blockIdx.x;
  int b = (blk*16) >> 13;           // 16 divides 8192: no batch straddle
  const float* cb = points + (size_t)b*NPTS*3;
  int qbase = blk*16 + wid*4;
  float qx[4],qy[4],qz[4],qpn[4],lmin[4],tq[4];
  #pragma unroll
  for (int q=0;q<4;++q){
    const float* qp = points + (size_t)(qbase+q)*3;
    qx[q]=qp[0]; qy[q]=qp[1]; qz[q]=qp[2];
    qpn[q]=fmaf(qz[q],qz[q],fmaf(qy[q],qy[q],qx[q]*qx[q]));
    lmin[q]=3.4e38f;
  }
  if (lane < 4) svC[wid*4+lane] = 0;   // own wave's counters only
  // ---- phase 1: per-query lane minima over lane-strided candidates ----
  #pragma unroll 4
  for (int s=0;s<128;++s){
    int p = s*64 + lane;
    const float* sp = cb + (size_t)p*3;
    float x=sp[0], y=sp[1], z=sp[2];
    float w = fmaf(z,z,fmaf(y,y,x*x));
    #pragma unroll
    for (int q=0;q<4;++q){
      float d = dist2f(qx[q],qy[q],qz[q],qpn[q], x,y,z,w);
      lmin[q] = fminf(lmin[q], d);
    }
  }
  // bitonic sort of 64 lane minima per query; t = 16th smallest
  #pragma unroll
  for (int q=0;q<4;++q){
    float v = lmin[q];
    #pragma unroll
    for (int k=2;k<=64;k<<=1){
      #pragma unroll
      for (int j=k>>1;j>=1;j>>=1){
        float o = __shfl_xor(v, j);
        bool keepmin = ((lane & j)==0) == ((lane & k)==0);
        v = keepmin ? fminf(v,o) : fmaxf(v,o);
      }
    }
    tq[q] = __shfl(v, 15);
  }
  // ---- phase 2: collect survivors d <= t (E[~18], 64 slots) ----
  #pragma unroll 2
  for (int s=0;s<128;++s){
    int p = s*64 + lane;
    const float* sp = cb + (size_t)p*3;
    float x=sp[0], y=sp[1], z=sp[2];
    float w = fmaf(z,z,fmaf(y,y,x*x));
    #pragma unroll
    for (int q=0;q<4;++q){
      float d = dist2f(qx[q],qy[q],qz[q],qpn[q], x,y,z,w);
      if (d <= tq[q]){
        int wq = wid*4+q;
        int slot = atomicAdd(&svC[wq], 1);
        if (slot < 64){ svD[wq][slot]=d; svI[wq][slot]=p; }
      }
    }
  }
  __syncthreads();   // insurance only (buffers are wave-private)
  // ---- final: rank-by-count selection per query ----
  #pragma unroll 1
  for (int q=0;q<4;++q){
    int wq = wid*4+q;
    int n = svC[wq]; n = (n>64)?64:n;   // n >= 16 guaranteed
    float d = (lane<n)? svD[wq][lane] : 3.4e38f;
    int   ii = (lane<n)? svI[wq][lane] : 0x7fffffff;
    int rank = 0;
    #pragma unroll 4
    for (int j=0;j<n;++j){              // broadcast LDS reads, conflict-free
      float od = svD[wq][j]; int oi = svI[wq][j];
      rank += ((od<d)||(od==d && oi<ii)) ? 1 : 0;
    }
    if (lane<n && rank<16) idxb[(size_t)(qbase+q)*16 + rank] = ii;
  }
}

// thread-per-query BN-d statistics over pos1 = Wd1*(q - nbr) + bd1
__global__ __launch_bounds__(256) void k_dstats(const int* __restrict__ idxb,
    const float* __restrict__ points, const float* __restrict__ Wd1, const float* __restrict__ bd1,
    float* __restrict__ stats){
  __shared__ float sS[6];
  if (threadIdx.x < 6) sS[threadIdx.x]=0.f;
  __syncthreads();
  int qi = blockIdx.x*256 + threadIdx.x;
  int b = qi >> 13;
  const float* qp = points + (size_t)qi*3;
  float qx=qp[0],qy=qp[1],qz=qp[2];
  float w00=Wd1[0],w01=Wd1[1],w02=Wd1[2],w10=Wd1[3],w11=Wd1[4],w12=Wd1[5],w20=Wd1[6],w21=Wd1[7],w22=Wd1[8];
  float b0=bd1[0],b1=bd1[1],b2=bd1[2];
  float s0=0,s1=0,s2=0,q0=0,q1=0,q2=0;
  #pragma unroll
  for (int j=0;j<16;j++){
    int nb = idxb[(size_t)qi*16 + j];
    const float* np_ = points + (size_t)(b*NPTS + nb)*3;
    float dx=qx-np_[0], dy=qy-np_[1], dz=qz-np_[2];
    float t0 = fmaf(dz,w02,fmaf(dy,w01,dx*w00)) + b0;
    float t1 = fmaf(dz,w12,fmaf(dy,w11,dx*w10)) + b1;
    float t2 = fmaf(dz,w22,fmaf(dy,w21,dx*w20)) + b2;
    s0+=t0; s1+=t1; s2+=t2;
    q0=fmaf(t0,t0,q0); q1=fmaf(t1,t1,q1); q2=fmaf(t2,t2,q2);
  }
  atomicAdd(&sS[0],s0); atomicAdd(&sS[1],s1); atomicAdd(&sS[2],s2);
  atomicAdd(&sS[3],q0); atomicAdd(&sS[4],q1); atomicAdd(&sS[5],q2);
  __syncthreads();
  if (threadIdx.x < 3) atomicAdd(&stats[SD_SUM+threadIdx.x], sS[threadIdx.x]);
  else if (threadIdx.x < 6) atomicAdd(&stats[SD_SSQ+threadIdx.x-3], sS[threadIdx.x]);
}

__global__ void k_finalize(float* stats, int sumOff, int ssqOff, const float* __restrict__ gm,
                           const float* __restrict__ bt, int scOff, int shOff, int C){
  int c = blockIdx.x*64 + threadIdx.x;
  if (c >= C) return;
  float m = stats[sumOff+c] * (1.0f/STAT_CNT);
  float v = stats[ssqOff+c] * (1.0f/STAT_CNT) - m*m;
  v = fmaxf(v, 0.0f);
  float rs = rsqrtf(v + BN_EPS);
  float sc = gm[c]*rs;
  stats[scOff+c] = sc;
  stats[shOff+c] = fmaf(-m, sc, bt[c]);
}

// finalize from 32 partial slots of [sum128, ssq128]
__global__ void k_finalizeP(float* stats, int partOff, const float* __restrict__ gm,
                            const float* __restrict__ bt, int scOff, int shOff){
  int c = blockIdx.x*64 + threadIdx.x;   // 2 blocks x 64
  float s=0.f, q=0.f;
  #pragma unroll 4
  for (int p=0;p<32;p++){
    s += stats[partOff + p*256 + c];
    q += stats[partOff + p*256 + 128 + c];
  }
  float m = s * (1.0f/STAT_CNT);
  float v = fmaxf(q*(1.0f/STAT_CNT) - m*m, 0.0f);
  float rs = rsqrtf(v + BN_EPS);
  float sc = gm[c]*rs;
  stats[scOff+c] = sc;
  stats[shOff+c] = fmaf(-m, sc, bt[c]);
}

// fused Q/K/V projection over contiguous feature rows: 64 rows/block, 4 waves.
// Q stored fp32 (qbuf); K,V stored bf16 with bias folded (kb, vb).
__global__ __launch_bounds__(256) void k_qkv(
    const unsigned short* __restrict__ featb, const unsigned short* __restrict__ wbf,
    const float* __restrict__ bq, const float* __restrict__ bk, const float* __restrict__ bv,
    float* __restrict__ qout, unsigned short* __restrict__ kout, unsigned short* __restrict__ vout)
{
  __shared__ __align__(16) unsigned short sA[64*128];
  int tid = threadIdx.x;
  size_t row0g = (size_t)blockIdx.x*64;
  for (int t=tid; t<1024; t+=256){
    int row=t>>4, cc=t&15;
    uint4 v = *(const uint4*)(featb + (row0g+row)*128 + cc*8);
    *(uint4*)((char*)sA + swz(row, cc*16)) = v;
  }
  __syncthreads();
  int wid=tid>>6, lane=tid&63;
  int r=lane&15, g=lane>>4;
  int row0 = wid*16;
  f32x4 aQ[8]={}, aK[8]={}, aV[8]={};
  const unsigned short* WQ = wbf;
  const unsigned short* WK = wbf+16384;
  const unsigned short* WV = wbf+32768;
  #pragma unroll
  for (int ks=0;ks<4;++ks){
    int k = ks*32 + g*8;
    bf16x8 a0 = ldsA8(sA, row0+r, k);
    #pragma unroll
    for (int nt=0;nt<8;++nt){
      aQ[nt]=MFMA16(a0, ldW8(WQ,nt*16+r,k), aQ[nt]);
      aK[nt]=MFMA16(a0, ldW8(WK,nt*16+r,k), aK[nt]);
      aV[nt]=MFMA16(a0, ldW8(WV,nt*16+r,k), aV[nt]);
    }
  }
  #pragma unroll
  for (int nt=0;nt<8;++nt){
    int ch=nt*16+r;
    float bqc=bq[ch], bkc=bk[ch], bvc=bv[ch];
    #pragma unroll
    for (int rr=0;rr<4;++rr){
      size_t grow = row0g + row0 + g*4 + rr;
      qout[grow*128+ch] = aQ[nt][rr]+bqc;
      kout[grow*128+ch] = f2b(aK[nt][rr]+bkc);
      vout[grow*128+ch] = f2b(aV[nt][rr]+bvc);
    }
  }
}

// streaming fusion: gamma1 = q - gather(K) + pos ; val = gather(V) + pos.
__global__ __launch_bounds__(256) void k_fuse(
    const float* __restrict__ points, const int* __restrict__ idxb,
    const float* __restrict__ qbuf, const unsigned short* __restrict__ kb,
    const unsigned short* __restrict__ vb,
    const float* __restrict__ Wd1, const float* __restrict__ bd1,
    const float* __restrict__ Wd2, const float* __restrict__ bd2,
    float* __restrict__ stats,
    unsigned short* __restrict__ g1out, unsigned short* __restrict__ valout)
{
  __shared__ float sSum[128];
  __shared__ float sSq[128];
  int tid = threadIdx.x, blk = blockIdx.x;
  int slot = tid & 15, jg = tid >> 4;
  int lane = tid & 63;
  int ch0 = slot*8;
  if (tid < 128){ sSum[tid]=0.f; sSq[tid]=0.f; }
  float w2[24], b2v[8];
  #pragma unroll
  for (int u=0;u<8;++u){
    w2[u*3+0]=Wd2[(ch0+u)*3+0];
    w2[u*3+1]=Wd2[(ch0+u)*3+1];
    w2[u*3+2]=Wd2[(ch0+u)*3+2];
    b2v[u]=bd2[ch0+u];
  }
  int c = slot & 3; c = (c==3)?2:c;
  float wa  = (c==0)?Wd1[0]:((c==1)?Wd1[3]:Wd1[6]);
  float wb_ = (c==0)?Wd1[1]:((c==1)?Wd1[4]:Wd1[7]);
  float wc  = (c==0)?Wd1[2]:((c==1)?Wd1[5]:Wd1[8]);
  float bc_ = (c==0)?bd1[0]:((c==1)?bd1[1]:bd1[2]);
  float sc_ = (c==0)?stats[SD_SC+0]:((c==1)?stats[SD_SC+1]:stats[SD_SC+2]);
  float sh_ = (c==0)?stats[SD_SH+0]:((c==1)?stats[SD_SH+1]:stats[SD_SH+2]);
  int base = lane & 48;
  float accS[8]={0,0,0,0,0,0,0,0}, accQ[8]={0,0,0,0,0,0,0,0};
  __syncthreads();
  #pragma unroll 2
  for (int i=0;i<8;++i){
    int q = blk*8 + i;
    int b = q >> 13;
    int row = q*16 + jg;
    int nb = idxb[row];
    const float* ctr = points + (size_t)q*3;
    const float* np_ = points + (size_t)(b*NPTS + nb)*3;
    float dx = ctr[0]-np_[0], dy = ctr[1]-np_[1], dz = ctr[2]-np_[2];
    float t = fmaf(dz, wc, fmaf(dy, wb_, dx*wa)) + bc_;
    float tc = gelu_f(fmaf(t, sc_, sh_));
    float g0  = __shfl(tc, base+0);
    float g1v = __shfl(tc, base+1);
    float g2v = __shfl(tc, base+2);
    size_t kvoff = ((size_t)(b*NPTS + nb))*128 + ch0;
    union { uint4 u; unsigned short s[8]; } K, V, G, Vo;
    K.u = *(const uint4*)(kb + kvoff);
    V.u = *(const uint4*)(vb + kvoff);
    float4 q0 = *(const float4*)(qbuf + (size_t)q*128 + ch0);
    float4 q1 = *(const float4*)(qbuf + (size_t)q*128 + ch0 + 4);
    float qv[8] = {q0.x,q0.y,q0.z,q0.w,q1.x,q1.y,q1.z,q1.w};
    #pragma unroll
    for (int u=0;u<8;++u){
      float pos = fmaf(g2v, w2[u*3+2], fmaf(g1v, w2[u*3+1], g0*w2[u*3+0])) + b2v[u];
      float key = b2f(K.s[u]);
      float val = b2f(V.s[u]) + pos;
      float gmv = qv[u] - key + pos;
      accS[u] += gmv; accQ[u] = fmaf(gmv,gmv,accQ[u]);
      G.s[u] = f2b(gmv); Vo.s[u] = f2b(val);
    }
    *(uint4*)(g1out + (size_t)row*128 + ch0) = G.u;
    *(uint4*)(valout + (size_t)row*128 + ch0) = Vo.u;
  }
  #pragma unroll
  for (int u=0;u<8;++u){
    atomicAdd(&sSum[ch0+u], accS[u]);
    atomicAdd(&sSq[ch0+u], accQ[u]);
  }
  __syncthreads();
  if (tid < 128){
    int ps = blk & 31;
    atomicAdd(&stats[PG1 + ps*256 + tid], sSum[tid]);
    atomicAdd(&stats[PG1 + ps*256 + 128 + tid], sSq[tid]);
  }
}

// 64-row blocks (16KB LDS, grid 4096) for occupancy; cheap-erf gelu loader.
// R10 lesson: 128-row/33KB version sat at 25% occupancy + erff-dominated VALU.
__global__ __launch_bounds__(256) void k_g(
    const unsigned short* __restrict__ gin, const unsigned short* __restrict__ W,
    const float* __restrict__ bias, float* __restrict__ stats, int scOff, int shOff,
    unsigned short* __restrict__ gout, int partOff)
{
  __shared__ __align__(16) unsigned short sA[64*128];
  __shared__ float sSum[128];
  __shared__ float sSq[128];
  int tid = threadIdx.x;
  size_t row0 = (size_t)blockIdx.x*64;
  if (tid<128){ sSum[tid]=0.f; sSq[tid]=0.f; }
  for (int t=tid; t<1024; t+=256){
    int row=t>>4, c=t&15;
    union { uint4 u; unsigned short s[8]; } iv, ov;
    iv.u = *(const uint4*)(gin + (row0+row)*128 + c*8);
    #pragma unroll
    for (int u=0;u<8;u++){
      int ch = c*8+u;
      float x = b2f(iv.s[u]);
      x = gelu_f(fmaf(x, stats[scOff+ch], stats[shOff+ch]));
      ov.s[u] = f2b(x);
    }
    *(uint4*)((char*)sA + swz(row, c*16)) = ov.u;
  }
  __syncthreads();
  int wid=tid>>6, lane=tid&63;
  int r=lane&15, g=lane>>4;
  int row0l = wid*16;
  f32x4 acc[8] = {};
  #pragma unroll
  for (int ks=0;ks<4;++ks){
    int k = ks*32 + g*8;
    bf16x8 a0 = ldsA8(sA, row0l+r, k);
    #pragma unroll
    for (int nt=0;nt<8;++nt)
      acc[nt] = MFMA16(a0, ldW8(W,nt*16+r,k), acc[nt]);
  }
  #pragma unroll
  for (int nt=0;nt<8;++nt){
    int ch = nt*16+r;
    float bc = bias[ch];
    float s_=0.f, qq=0.f;
    #pragma unroll
    for (int rr=0;rr<4;++rr){
      int row = row0l + g*4 + rr;
      float x = acc[nt][rr] + bc;
      s_ += x; qq = fmaf(x,x,qq);
      gout[(row0+row)*128 + ch] = f2b(x);
    }
    atomicAdd(&sSum[ch], s_); atomicAdd(&sSq[ch], qq);
  }
  __syncthreads();
  if (tid<128){
    int slot = blockIdx.x & 31;
    atomicAdd(&stats[partOff + slot*256 + tid], sSum[tid]);
    atomicAdd(&stats[partOff + slot*256 + 128 + tid], sSq[tid]);
  }
}

// 64-row blocks (32KB LDS, grid 4096); each wave owns exactly one query's 16
// neighbor rows -> softmax reduction stays in-wave (rr + shfl_xor 16/32).
__global__ __launch_bounds__(256) void k_out(
    const unsigned short* __restrict__ gin, const unsigned short* __restrict__ W,
    const float* __restrict__ bias, const float* __restrict__ stats, int scOff, int shOff,
    const unsigned short* __restrict__ val, float* __restrict__ outp)
{
  __shared__ __align__(16) unsigned short sA[64*128];
  __shared__ __align__(16) unsigned short sV[64*128];
  int tid=threadIdx.x;
  size_t row0=(size_t)blockIdx.x*64;
  for (int t=tid;t<1024;t+=256){
    int row=t>>4,c=t&15;
    union { uint4 u; unsigned short s[8]; } iv, ov;
    iv.u = *(const uint4*)(gin + (row0+row)*128 + c*8);
    #pragma unroll
    for (int u=0;u<8;u++){
      int ch=c*8+u;
      float x = b2f(iv.s[u]);
      x = gelu_f(fmaf(x, stats[scOff+ch], stats[shOff+ch]));
      ov.s[u]=f2b(x);
    }
    *(uint4*)((char*)sA + swz(row,c*16)) = ov.u;
    uint4 vv = *(const uint4*)(val + (row0+row)*128 + c*8);
    *(uint4*)((char*)sV + swz(row,c*16)) = vv;
  }
  __syncthreads();
  int wid=tid>>6, lane=tid&63;
  int r=lane&15, g=lane>>4;
  int row0l = wid*16;
  f32x4 acc[8] = {};
  #pragma unroll
  for (int ks=0;ks<4;++ks){
    int k = ks*32 + g*8;
    bf16x8 a0 = ldsA8(sA, row0l+r, k);
    #pragma unroll
    for (int nt=0;nt<8;++nt)
      acc[nt] = MFMA16(a0, ldW8(W,nt*16+r,k), acc[nt]);
  }
  #pragma unroll
  for (int nt=0;nt<8;++nt){
    int ch=nt*16+r; float bc=bias[ch];
    float g3[4], vv[4];
    #pragma unroll
    for (int rr=0;rr<4;++rr){
      int row=row0l+g*4+rr;
      g3[rr]=acc[nt][rr]+bc;
      vv[rr]=b2f(*(const unsigned short*)((const char*)sV + swz(row, ch*2)));
    }
    float m = fmaxf(fmaxf(g3[0],g3[1]),fmaxf(g3[2],g3[3]));
    m = fmaxf(m, __shfl_xor(m,16));
    m = fmaxf(m, __shfl_xor(m,32));
    float s=0.f, o=0.f;
    #pragma unroll
    for (int rr=0;rr<4;++rr){
      float e = __expf(g3[rr]-m);
      s += e; o = fmaf(e, vv[rr], o);
    }
    s += __shfl_xor(s,16); s += __shfl_xor(s,32);
    o += __shfl_xor(o,16); o += __shfl_xor(o,32);
    if (g==0){
      outp[((size_t)blockIdx.x*4 + wid)*128 + ch] = o/s;
    }
  }
}

extern "C" void kernel_launch(void* const* d_in, const int* in_sizes, int n_in,
                              void* d_out, int out_size, void* d_ws, size_t ws_size,
                              hipStream_t stream)
{
  const float* feats  = (const float*)d_in[0];
  const float* points = (const float*)d_in[1];
  const float* Wq = (const float*)d_in[2];  const float* bq = (const float*)d_in[3];
  const float* Wk = (const float*)d_in[4];  const float* bk = (const float*)d_in[5];
  const float* Wv = (const float*)d_in[6];  const float* bv = (const float*)d_in[7];
  const float* Wd1= (const float*)d_in[8];  const float* bd1= (const float*)d_in[9];
  const float* Wd2= (const float*)d_in[10]; const float* bd2= (const float*)d_in[11];
  const float* Wg1= (const float*)d_in[12]; const float* bg1= (const float*)d_in[13];
  const float* Wg2= (const float*)d_in[14]; const float* bg2= (const float*)d_in[15];
  const float* gd = (const float*)d_in[16]; const float* betad = (const float*)d_in[17];
  const float* gg1= (const float*)d_in[18]; const float* betag1= (const float*)d_in[19];
  const float* gg2= (const float*)d_in[20]; const float* betag2= (const float*)d_in[21];
  float* outp = (float*)d_out;

  char* ws = (char*)d_ws;
  int*    idxb  = (int*)   (ws + 0);                         // 1 MB
  float*  stats = (float*) (ws + 1048576);                   // ~68 KB
  unsigned short* wbf   = (unsigned short*)(ws + 1179648);   // 160 KB
  unsigned short* featb = (unsigned short*)(ws + 1343488);   // 4 MB
  unsigned short* kb    = (unsigned short*)(ws + 5537792);   // 4 MB
  unsigned short* vbuf  = (unsigned short*)(ws + 9732096);   // 4 MB
  unsigned short* g1b = (unsigned short*)(ws + 13926400);    // 64 MB
  unsigned short* vab = (unsigned short*)(ws + 81035264);    // 64 MB
  unsigned short* g2b = (unsigned short*)(ws + 148144128);   // 64 MB
  float*  qbuf  = (float*) (ws + 215252992);                 // 8 MB (ends 223.45MB, within R1-proven 223.5MB)

  k_prep<<<dim3(8192),dim3(256),0,stream>>>(feats,Wq,Wk,Wv,Wg1,Wg2,wbf,featb,stats);
  k_knn5<<<dim3(1024),dim3(256),0,stream>>>(points,idxb);
  k_dstats<<<dim3(64),dim3(256),0,stream>>>(idxb,points,Wd1,bd1,stats);
  k_finalize<<<dim3(1),dim3(64),0,stream>>>(stats,SD_SUM,SD_SSQ,gd,betad,SD_SC,SD_SH,3);
  k_qkv<<<dim3(256),dim3(256),0,stream>>>(featb,wbf,bq,bk,bv,qbuf,kb,vbuf);
  k_fuse<<<dim3(2048),dim3(256),0,stream>>>(points,idxb,qbuf,kb,vbuf,Wd1,bd1,Wd2,bd2,stats,g1b,vab);
  k_finalizeP<<<dim3(2),dim3(64),0,stream>>>(stats,PG1,gg1,betag1,SG1_SC,SG1_SH);
  k_g<<<dim3(4096),dim3(256),0,stream>>>(g1b,wbf+49152,bg1,stats,SG1_SC,SG1_SH,g2b,PG2);
  k_finalizeP<<<dim3(2),dim3(64),0,stream>>>(stats,PG2,gg2,betag2,SG2_SC,SG2_SH);
  k_out<<<dim3(4096),dim3(256),0,stream>>>(g2b,wbf+65536,bg2,stats,SG2_SC,SG2_SH,vab,outp);
  (void)in_sizes; (void)n_in; (void)out_size; (void)ws_size;
}

// Round 12
// 347.300 us; speedup vs baseline: 1.1798x; 1.1798x over previous
//
#include <hip/hip_runtime.h>
#include <hip/hip_bf16.h>
#include <math.h>

#define NPTS 8192
#define STAT_CNT 262144.0f
#define BN_EPS 1e-5f

typedef __attribute__((__ext_vector_type__(8))) __bf16 bf16x8;
typedef __attribute__((__ext_vector_type__(4))) float f32x4;

// stats region float offsets
#define SD_SUM 0
#define SD_SSQ 4
#define SD_SC 8
#define SD_SH 12
#define SG1_SC 16
#define SG1_SH 144
#define SG2_SC 272
#define SG2_SH 400
#define PG1 528
#define PG2 8720
#define STATS_FLOATS 16912

__device__ __forceinline__ unsigned short f2b(float x){
  unsigned u = __float_as_uint(x);
  return (unsigned short)((u + 0x7FFFu + ((u>>16)&1u)) >> 16);
}
__device__ __forceinline__ float b2f(unsigned short h){
  return __uint_as_float(((unsigned)h)<<16);
}
// gelu with A&S 7.1.26 erf approx: |err| <= 1.5e-7 absolute.
__device__ __forceinline__ float gelu_f(float x){
  float u = fabsf(x)*0.70710678118654752440f;
  float t = 1.0f/fmaf(0.3275911f, u, 1.0f);
  float p = t*fmaf(t,fmaf(t,fmaf(t,fmaf(t,1.061405429f,-1.453152027f),1.421413741f),-0.284496736f),0.254829592f);
  float er = fmaf(-p, __expf(-u*u), 1.0f);
  er = (x < 0.f) ? -er : er;
  return 0.5f*x*(1.0f+er);
}
// XOR-swizzled LDS addressing for [rows][256B] bf16 tiles (G4 fix)
__device__ __forceinline__ int swz(int row, int byteInRow){
  return row*256 + (byteInRow ^ ((row&7)<<4));
}
__device__ __forceinline__ float dist2f(float qx,float qy,float qz,float qpn,
                                        float x,float y,float z,float w){
  return (qpn + w) - 2.0f*fmaf(qx,x,fmaf(qy,y,qz*z));
}

#define MFMA16(a,b,c) __builtin_amdgcn_mfma_f32_16x16x32_bf16((a),(b),(c),0,0,0)

__device__ __forceinline__ bf16x8 ldsA8(const unsigned short* sA, int row, int k){
  return *(const bf16x8*)((const char*)sA + swz(row, k*2));
}
__device__ __forceinline__ bf16x8 ldW8(const unsigned short* W, int n, int k){
  return *(const bf16x8*)(W + n*128 + k);
}

// in-register bf16x8 -> BN -> gelu -> bf16x8 (channels kb0..kb0+7 via LDS sc/sh)
__device__ __forceinline__ bf16x8 bn_gelu8(uint4 raw, const float* sSC, const float* sSH, int kb0){
  union { f32x4 v[2]; float f[8]; } SC, SH;
  SC.v[0] = *(const f32x4*)&sSC[kb0]; SC.v[1] = *(const f32x4*)&sSC[kb0+4];
  SH.v[0] = *(const f32x4*)&sSH[kb0]; SH.v[1] = *(const f32x4*)&sSH[kb0+4];
  union { uint4 u; unsigned int w[4]; } U; U.u = raw;
  union { unsigned int w[4]; bf16x8 v; } O;
  #pragma unroll
  for (int p=0;p<4;++p){
    float xlo = gelu_f(fmaf(__uint_as_float(U.w[p]<<16),        SC.f[2*p],   SH.f[2*p]));
    float xhi = gelu_f(fmaf(__uint_as_float(U.w[p]&0xffff0000u), SC.f[2*p+1], SH.f[2*p+1]));
    unsigned lo = __float_as_uint(xlo), hi = __float_as_uint(xhi);
    lo = (lo + 0x7FFFu + ((lo>>16)&1u)) >> 16;
    hi = (hi + 0x7FFFu + ((hi>>16)&1u)) & 0xffff0000u;
    O.w[p] = hi | lo;
  }
  return O.v;
}

__global__ __launch_bounds__(256) void k_prep(
    const float* __restrict__ feats, const float* __restrict__ Wq, const float* __restrict__ Wk,
    const float* __restrict__ Wv, const float* __restrict__ Wg1, const float* __restrict__ Wg2,
    unsigned short* __restrict__ wbf, unsigned short* __restrict__ featb, float* __restrict__ stats)
{
  int i = blockIdx.x*256 + threadIdx.x;   // grid covers exactly 2097152
  featb[i] = f2b(feats[i]);
  if (i < 16384){
    wbf[i]        = f2b(Wq[i]);
    wbf[16384+i]  = f2b(Wk[i]);
    wbf[32768+i]  = f2b(Wv[i]);
    wbf[49152+i]  = f2b(Wg1[i]);
    wbf[65536+i]  = f2b(Wg2[i]);
  }
  if (i < STATS_FLOATS) stats[i] = 0.f;
}

// barrier-free threshold-filter kNN (R10-proven): 4 queries/wave, global reads,
// wave-private survivor buffers, rank-by-count selection.
__global__ __launch_bounds__(256) void k_knn5(const float* __restrict__ points, int* __restrict__ idxb){
  __shared__ float svD[16][64];
  __shared__ int   svI[16][64];
  __shared__ int   svC[16];
  int tid = threadIdx.x;
  int wid = tid>>6, lane = tid&63;
  int blk = blockIdx.x;
  int b = (blk*16) >> 13;           // 16 divides 8192: no batch straddle
  const float* cb = points + (size_t)b*NPTS*3;
  int qbase = blk*16 + wid*4;
  float qx[4],qy[4],qz[4],qpn[4],lmin[4],tq[4];
  #pragma unroll
  for (int q=0;q<4;++q){
    const float* qp = points + (size_t)(qbase+q)*3;
    qx[q]=qp[0]; qy[q]=qp[1]; qz[q]=qp[2];
    qpn[q]=fmaf(qz[q],qz[q],fmaf(qy[q],qy[q],qx[q]*qx[q]));
    lmin[q]=3.4e38f;
  }
  if (lane < 4) svC[wid*4+lane] = 0;
  #pragma unroll 4
  for (int s=0;s<128;++s){
    int p = s*64 + lane;
    const float* sp = cb + (size_t)p*3;
    float x=sp[0], y=sp[1], z=sp[2];
    float w = fmaf(z,z,fmaf(y,y,x*x));
    #pragma unroll
    for (int q=0;q<4;++q){
      float d = dist2f(qx[q],qy[q],qz[q],qpn[q], x,y,z,w);
      lmin[q] = fminf(lmin[q], d);
    }
  }
  #pragma unroll
  for (int q=0;q<4;++q){
    float v = lmin[q];
    #pragma unroll
    for (int k=2;k<=64;k<<=1){
      #pragma unroll
      for (int j=k>>1;j>=1;j>>=1){
        float o = __shfl_xor(v, j);
        bool keepmin = ((lane & j)==0) == ((lane & k)==0);
        v = keepmin ? fminf(v,o) : fmaxf(v,o);
      }
    }
    tq[q] = __shfl(v, 15);
  }
  #pragma unroll 2
  for (int s=0;s<128;++s){
    int p = s*64 + lane;
    const float* sp = cb + (size_t)p*3;
    float x=sp[0], y=sp[1], z=sp[2];
    float w = fmaf(z,z,fmaf(y,y,x*x));
    #pragma unroll
    for (int q=0;q<4;++q){
      float d = dist2f(qx[q],qy[q],qz[q],qpn[q], x,y,z,w);
      if (d <= tq[q]){
        int wq = wid*4+q;
        int slot = atomicAdd(&svC[wq], 1);
        if (slot < 64){ svD[wq][slot]=d; svI[wq][slot]=p; }
      }
    }
  }
  __syncthreads();
  #pragma unroll 1
  for (int q=0;q<4;++q){
    int wq = wid*4+q;
    int n = svC[wq]; n = (n>64)?64:n;
    float d = (lane<n)? svD[wq][lane] : 3.4e38f;
    int   ii = (lane<n)? svI[wq][lane] : 0x7fffffff;
    int rank = 0;
    #pragma unroll 4
    for (int j=0;j<n;++j){
      float od = svD[wq][j]; int oi = svI[wq][j];
      rank += ((od<d)||(od==d && oi<ii)) ? 1 : 0;
    }
    if (lane<n && rank<16) idxb[(size_t)(qbase+q)*16 + rank] = ii;
  }
}

// thread-per-query BN-d statistics over pos1 = Wd1*(q - nbr) + bd1
__global__ __launch_bounds__(256) void k_dstats(const int* __restrict__ idxb,
    const float* __restrict__ points, const float* __restrict__ Wd1, const float* __restrict__ bd1,
    float* __restrict__ stats){
  __shared__ float sS[6];
  if (threadIdx.x < 6) sS[threadIdx.x]=0.f;
  __syncthreads();
  int qi = blockIdx.x*256 + threadIdx.x;
  int b = qi >> 13;
  const float* qp = points + (size_t)qi*3;
  float qx=qp[0],qy=qp[1],qz=qp[2];
  float w00=Wd1[0],w01=Wd1[1],w02=Wd1[2],w10=Wd1[3],w11=Wd1[4],w12=Wd1[5],w20=Wd1[6],w21=Wd1[7],w22=Wd1[8];
  float b0=bd1[0],b1=bd1[1],b2=bd1[2];
  float s0=0,s1=0,s2=0,q0=0,q1=0,q2=0;
  #pragma unroll
  for (int j=0;j<16;j++){
    int nb = idxb[(size_t)qi*16 + j];
    const float* np_ = points + (size_t)(b*NPTS + nb)*3;
    float dx=qx-np_[0], dy=qy-np_[1], dz=qz-np_[2];
    float t0 = fmaf(dz,w02,fmaf(dy,w01,dx*w00)) + b0;
    float t1 = fmaf(dz,w12,fmaf(dy,w11,dx*w10)) + b1;
    float t2 = fmaf(dz,w22,fmaf(dy,w21,dx*w20)) + b2;
    s0+=t0; s1+=t1; s2+=t2;
    q0=fmaf(t0,t0,q0); q1=fmaf(t1,t1,q1); q2=fmaf(t2,t2,q2);
  }
  atomicAdd(&sS[0],s0); atomicAdd(&sS[1],s1); atomicAdd(&sS[2],s2);
  atomicAdd(&sS[3],q0); atomicAdd(&sS[4],q1); atomicAdd(&sS[5],q2);
  __syncthreads();
  if (threadIdx.x < 3) atomicAdd(&stats[SD_SUM+threadIdx.x], sS[threadIdx.x]);
  else if (threadIdx.x < 6) atomicAdd(&stats[SD_SSQ+threadIdx.x-3], sS[threadIdx.x]);
}

__global__ void k_finalize(float* stats, int sumOff, int ssqOff, const float* __restrict__ gm,
                           const float* __restrict__ bt, int scOff, int shOff, int C){
  int c = blockIdx.x*64 + threadIdx.x;
  if (c >= C) return;
  float m = stats[sumOff+c] * (1.0f/STAT_CNT);
  float v = stats[ssqOff+c] * (1.0f/STAT_CNT) - m*m;
  v = fmaxf(v, 0.0f);
  float rs = rsqrtf(v + BN_EPS);
  float sc = gm[c]*rs;
  stats[scOff+c] = sc;
  stats[shOff+c] = fmaf(-m, sc, bt[c]);
}

// finalize from 32 partial slots of [sum128, ssq128]
__global__ void k_finalizeP(float* stats, int partOff, const float* __restrict__ gm,
                            const float* __restrict__ bt, int scOff, int shOff){
  int c = blockIdx.x*64 + threadIdx.x;   // 2 blocks x 64
  float s=0.f, q=0.f;
  #pragma unroll 4
  for (int p=0;p<32;p++){
    s += stats[partOff + p*256 + c];
    q += stats[partOff + p*256 + 128 + c];
  }
  float m = s * (1.0f/STAT_CNT);
  float v = fmaxf(q*(1.0f/STAT_CNT) - m*m, 0.0f);
  float rs = rsqrtf(v + BN_EPS);
  float sc = gm[c]*rs;
  stats[scOff+c] = sc;
  stats[shOff+c] = fmaf(-m, sc, bt[c]);
}

// fused Q/K/V projection over contiguous feature rows: 64 rows/block, 4 waves.
__global__ __launch_bounds__(256) void k_qkv(
    const unsigned short* __restrict__ featb, const unsigned short* __restrict__ wbf,
    const float* __restrict__ bq, const float* __restrict__ bk, const float* __restrict__ bv,
    float* __restrict__ qout, unsigned short* __restrict__ kout, unsigned short* __restrict__ vout)
{
  __shared__ __align__(16) unsigned short sA[64*128];
  int tid = threadIdx.x;
  size_t row0g = (size_t)blockIdx.x*64;
  for (int t=tid; t<1024; t+=256){
    int row=t>>4, cc=t&15;
    uint4 v = *(const uint4*)(featb + (row0g+row)*128 + cc*8);
    *(uint4*)((char*)sA + swz(row, cc*16)) = v;
  }
  __syncthreads();
  int wid=tid>>6, lane=tid&63;
  int r=lane&15, g=lane>>4;
  int row0 = wid*16;
  f32x4 aQ[8]={}, aK[8]={}, aV[8]={};
  const unsigned short* WQ = wbf;
  const unsigned short* WK = wbf+16384;
  const unsigned short* WV = wbf+32768;
  #pragma unroll
  for (int ks=0;ks<4;++ks){
    int k = ks*32 + g*8;
    bf16x8 a0 = ldsA8(sA, row0+r, k);
    #pragma unroll
    for (int nt=0;nt<8;++nt){
      aQ[nt]=MFMA16(a0, ldW8(WQ,nt*16+r,k), aQ[nt]);
      aK[nt]=MFMA16(a0, ldW8(WK,nt*16+r,k), aK[nt]);
      aV[nt]=MFMA16(a0, ldW8(WV,nt*16+r,k), aV[nt]);
    }
  }
  #pragma unroll
  for (int nt=0;nt<8;++nt){
    int ch=nt*16+r;
    float bqc=bq[ch], bkc=bk[ch], bvc=bv[ch];
    #pragma unroll
    for (int rr=0;rr<4;++rr){
      size_t grow = row0g + row0 + g*4 + rr;
      qout[grow*128+ch] = aQ[nt][rr]+bqc;
      kout[grow*128+ch] = f2b(aK[nt][rr]+bkc);
      vout[grow*128+ch] = f2b(aV[nt][rr]+bvc);
    }
  }
}

// streaming fusion: gamma1 = q - gather(K) + pos ; val = gather(V) + pos.
__global__ __launch_bounds__(256) void k_fuse(
    const float* __restrict__ points, const int* __restrict__ idxb,
    const float* __restrict__ qbuf, const unsigned short* __restrict__ kb,
    const unsigned short* __restrict__ vb,
    const float* __restrict__ Wd1, const float* __restrict__ bd1,
    const float* __restrict__ Wd2, const float* __restrict__ bd2,
    float* __restrict__ stats,
    unsigned short* __restrict__ g1out, unsigned short* __restrict__ valout)
{
  __shared__ float sSum[128];
  __shared__ float sSq[128];
  int tid = threadIdx.x, blk = blockIdx.x;
  int slot = tid & 15, jg = tid >> 4;
  int lane = tid & 63;
  int ch0 = slot*8;
  if (tid < 128){ sSum[tid]=0.f; sSq[tid]=0.f; }
  float w2[24], b2v[8];
  #pragma unroll
  for (int u=0;u<8;++u){
    w2[u*3+0]=Wd2[(ch0+u)*3+0];
    w2[u*3+1]=Wd2[(ch0+u)*3+1];
    w2[u*3+2]=Wd2[(ch0+u)*3+2];
    b2v[u]=bd2[ch0+u];
  }
  int c = slot & 3; c = (c==3)?2:c;
  float wa  = (c==0)?Wd1[0]:((c==1)?Wd1[3]:Wd1[6]);
  float wb_ = (c==0)?Wd1[1]:((c==1)?Wd1[4]:Wd1[7]);
  float wc  = (c==0)?Wd1[2]:((c==1)?Wd1[5]:Wd1[8]);
  float bc_ = (c==0)?bd1[0]:((c==1)?bd1[1]:bd1[2]);
  float sc_ = (c==0)?stats[SD_SC+0]:((c==1)?stats[SD_SC+1]:stats[SD_SC+2]);
  float sh_ = (c==0)?stats[SD_SH+0]:((c==1)?stats[SD_SH+1]:stats[SD_SH+2]);
  int base = lane & 48;
  float accS[8]={0,0,0,0,0,0,0,0}, accQ[8]={0,0,0,0,0,0,0,0};
  __syncthreads();
  #pragma unroll 2
  for (int i=0;i<8;++i){
    int q = blk*8 + i;
    int b = q >> 13;
    int row = q*16 + jg;
    int nb = idxb[row];
    const float* ctr = points + (size_t)q*3;
    const float* np_ = points + (size_t)(b*NPTS + nb)*3;
    float dx = ctr[0]-np_[0], dy = ctr[1]-np_[1], dz = ctr[2]-np_[2];
    float t = fmaf(dz, wc, fmaf(dy, wb_, dx*wa)) + bc_;
    float tc = gelu_f(fmaf(t, sc_, sh_));
    float g0  = __shfl(tc, base+0);
    float g1v = __shfl(tc, base+1);
    float g2v = __shfl(tc, base+2);
    size_t kvoff = ((size_t)(b*NPTS + nb))*128 + ch0;
    union { uint4 u; unsigned short s[8]; } K, V, G, Vo;
    K.u = *(const uint4*)(kb + kvoff);
    V.u = *(const uint4*)(vb + kvoff);
    float4 q0 = *(const float4*)(qbuf + (size_t)q*128 + ch0);
    float4 q1 = *(const float4*)(qbuf + (size_t)q*128 + ch0 + 4);
    float qv[8] = {q0.x,q0.y,q0.z,q0.w,q1.x,q1.y,q1.z,q1.w};
    #pragma unroll
    for (int u=0;u<8;++u){
      float pos = fmaf(g2v, w2[u*3+2], fmaf(g1v, w2[u*3+1], g0*w2[u*3+0])) + b2v[u];
      float key = b2f(K.s[u]);
      float val = b2f(V.s[u]) + pos;
      float gmv = qv[u] - key + pos;
      accS[u] += gmv; accQ[u] = fmaf(gmv,gmv,accQ[u]);
      G.s[u] = f2b(gmv); Vo.s[u] = f2b(val);
    }
    *(uint4*)(g1out + (size_t)row*128 + ch0) = G.u;
    *(uint4*)(valout + (size_t)row*128 + ch0) = Vo.u;
  }
  #pragma unroll
  for (int u=0;u<8;++u){
    atomicAdd(&sSum[ch0+u], accS[u]);
    atomicAdd(&sSq[ch0+u], accQ[u]);
  }
  __syncthreads();
  if (tid < 128){
    int ps = blk & 31;
    atomicAdd(&stats[PG1 + ps*256 + tid], sSum[tid]);
    atomicAdd(&stats[PG1 + ps*256 + 128 + tid], sSq[tid]);
  }
}

// persistent-wave stream-MFMA GEMM (R11 lesson: short phase-chained blocks
// pin at ~28% occupancy; W re-read per wave). W + BN sc/sh staged in LDS once
// (one barrier); then each wave independently grid-strides 16-row tiles:
// A-fragments loaded DIRECTLY from global (lane(r,g) <- row r, 16B chunk),
// BN+gelu applied in-register, MFMA vs LDS-W, scattered 2B stores.
__global__ __launch_bounds__(512) void k_g(
    const unsigned short* __restrict__ gin, const unsigned short* __restrict__ W,
    const float* __restrict__ bias, float* __restrict__ stats, int scOff, int shOff,
    unsigned short* __restrict__ gout, int partOff)
{
  __shared__ __align__(16) unsigned short sW[128*128];
  __shared__ float sSC[128], sSH[128];
  int tid = threadIdx.x;
  for (int t=tid; t<2048; t+=512){
    int row=t>>4, c=t&15;
    uint4 v = *(const uint4*)(W + row*128 + c*8);
    *(uint4*)((char*)sW + swz(row,c*16)) = v;
  }
  if (tid < 128){ sSC[tid]=stats[scOff+tid]; sSH[tid]=stats[shOff+tid]; }
  __syncthreads();
  int wid=tid>>6, lane=tid&63;
  int r=lane&15, g=lane>>4;
  float bs[8];
  #pragma unroll
  for (int nt=0;nt<8;++nt) bs[nt]=bias[nt*16+r];
  float accS[8]={0,0,0,0,0,0,0,0}, accQ[8]={0,0,0,0,0,0,0,0};
  for (int tile = blockIdx.x*8 + wid; tile < 16384; tile += 8192){
    size_t row0 = (size_t)tile*16;
    bf16x8 a[4];
    #pragma unroll
    for (int ks=0;ks<4;++ks){
      int kb0 = ks*32 + g*8;
      uint4 raw = *(const uint4*)(gin + (row0+r)*128 + kb0);
      a[ks] = bn_gelu8(raw, sSC, sSH, kb0);
    }
    f32x4 acc[8] = {};
    #pragma unroll
    for (int ks=0;ks<4;++ks){
      int k = ks*32 + g*8;
      #pragma unroll
      for (int nt=0;nt<8;++nt)
        acc[nt] = MFMA16(a[ks], ldsA8(sW, nt*16+r, k), acc[nt]);
    }
    #pragma unroll
    for (int nt=0;nt<8;++nt){
      #pragma unroll
      for (int rr=0;rr<4;++rr){
        float x = acc[nt][rr] + bs[nt];
        accS[nt] += x; accQ[nt] = fmaf(x,x,accQ[nt]);
        gout[(row0 + g*4 + rr)*128 + nt*16 + r] = f2b(x);
      }
    }
  }
  #pragma unroll
  for (int nt=0;nt<8;++nt){
    float s_ = accS[nt], q_ = accQ[nt];
    s_ += __shfl_xor(s_,16); s_ += __shfl_xor(s_,32);
    q_ += __shfl_xor(q_,16); q_ += __shfl_xor(q_,32);
    if (g==0){
      int slot = blockIdx.x & 31;
      atomicAdd(&stats[partOff + slot*256 + nt*16+r], s_);
      atomicAdd(&stats[partOff + slot*256 + 128 + nt*16+r], q_);
    }
  }
}

// persistent-wave stream-MFMA + in-wave softmax: tile == one query's 16
// neighbor rows. Softmax over rows = in-lane rr + shfl_xor over g (16,32).
__global__ __launch_bounds__(512) void k_out(
    const unsigned short* __restrict__ gin, const unsigned short* __restrict__ W,
    const float* __restrict__ bias, const float* __restrict__ stats, int scOff, int shOff,
    const unsigned short* __restrict__ val, float* __restrict__ outp)
{
  __shared__ __align__(16) unsigned short sW[128*128];
  __shared__ float sSC[128], sSH[128];
  int tid = threadIdx.x;
  for (int t=tid; t<2048; t+=512){
    int row=t>>4, c=t&15;
    uint4 v = *(const uint4*)(W + row*128 + c*8);
    *(uint4*)((char*)sW + swz(row,c*16)) = v;
  }
  if (tid < 128){ sSC[tid]=stats[scOff+tid]; sSH[tid]=stats[shOff+tid]; }
  __syncthreads();
  int wid=tid>>6, lane=tid&63;
  int r=lane&15, g=lane>>4;
  float bs[8];
  #pragma unroll
  for (int nt=0;nt<8;++nt) bs[nt]=bias[nt*16+r];
  for (int tile = blockIdx.x*8 + wid; tile < 16384; tile += 8192){
    size_t row0 = (size_t)tile*16;
    bf16x8 a[4];
    #pragma unroll
    for (int ks=0;ks<4;++ks){
      int kb0 = ks*32 + g*8;
      uint4 raw = *(const uint4*)(gin + (row0+r)*128 + kb0);
      a[ks] = bn_gelu8(raw, sSC, sSH, kb0);
    }
    f32x4 acc[8] = {};
    #pragma unroll
    for (int ks=0;ks<4;++ks){
      int k = ks*32 + g*8;
      #pragma unroll
      for (int nt=0;nt<8;++nt)
        acc[nt] = MFMA16(a[ks], ldsA8(sW, nt*16+r, k), acc[nt]);
    }
    #pragma unroll
    for (int nt=0;nt<8;++nt){
      float g3[4];
      #pragma unroll
      for (int rr=0;rr<4;++rr) g3[rr] = acc[nt][rr] + bs[nt];
      float m = fmaxf(fmaxf(g3[0],g3[1]),fmaxf(g3[2],g3[3]));
      m = fmaxf(m, __shfl_xor(m,16));
      m = fmaxf(m, __shfl_xor(m,32));
      float s=0.f, o=0.f;
      #pragma unroll
      for (int rr=0;rr<4;++rr){
        float e = __expf(g3[rr]-m);
        float vv = b2f(val[(row0 + g*4 + rr)*128 + nt*16 + r]);
        s += e; o = fmaf(e, vv, o);
      }
      s += __shfl_xor(s,16); s += __shfl_xor(s,32);
      o += __shfl_xor(o,16); o += __shfl_xor(o,32);
      if (g==0) outp[(size_t)tile*128 + nt*16 + r] = o/s;
    }
  }
}

extern "C" void kernel_launch(void* const* d_in, const int* in_sizes, int n_in,
                              void* d_out, int out_size, void* d_ws, size_t ws_size,
                              hipStream_t stream)
{
  const float* feats  = (const float*)d_in[0];
  const float* points = (const float*)d_in[1];
  const float* Wq = (const float*)d_in[2];  const float* bq = (const float*)d_in[3];
  const float* Wk = (const float*)d_in[4];  const float* bk = (const float*)d_in[5];
  const float* Wv = (const float*)d_in[6];  const float* bv = (const float*)d_in[7];
  const float* Wd1= (const float*)d_in[8];  const float* bd1= (const float*)d_in[9];
  const float* Wd2= (const float*)d_in[10]; const float* bd2= (const float*)d_in[11];
  const float* Wg1= (const float*)d_in[12]; const float* bg1= (const float*)d_in[13];
  const float* Wg2= (const float*)d_in[14]; const float* bg2= (const float*)d_in[15];
  const float* gd = (const float*)d_in[16]; const float* betad = (const float*)d_in[17];
  const float* gg1= (const float*)d_in[18]; const float* betag1= (const float*)d_in[19];
  const float* gg2= (const float*)d_in[20]; const float* betag2= (const float*)d_in[21];
  float* outp = (float*)d_out;

  char* ws = (char*)d_ws;
  int*    idxb  = (int*)   (ws + 0);                         // 1 MB
  float*  stats = (float*) (ws + 1048576);                   // ~68 KB
  unsigned short* wbf   = (unsigned short*)(ws + 1179648);   // 160 KB
  unsigned short* featb = (unsigned short*)(ws + 1343488);   // 4 MB
  unsigned short* kb    = (unsigned short*)(ws + 5537792);   // 4 MB
  unsigned short* vbuf  = (unsigned short*)(ws + 9732096);   // 4 MB
  unsigned short* g1b = (unsigned short*)(ws + 13926400);    // 64 MB
  unsigned short* vab = (unsigned short*)(ws + 81035264);    // 64 MB
  unsigned short* g2b = (unsigned short*)(ws + 148144128);   // 64 MB
  float*  qbuf  = (float*) (ws + 215252992);                 // 8 MB (ends 223.45MB)

  k_prep<<<dim3(8192),dim3(256),0,stream>>>(feats,Wq,Wk,Wv,Wg1,Wg2,wbf,featb,stats);
  k_knn5<<<dim3(1024),dim3(256),0,stream>>>(points,idxb);
  k_dstats<<<dim3(64),dim3(256),0,stream>>>(idxb,points,Wd1,bd1,stats);
  k_finalize<<<dim3(1),dim3(64),0,stream>>>(stats,SD_SUM,SD_SSQ,gd,betad,SD_SC,SD_SH,3);
  k_qkv<<<dim3(256),dim3(256),0,stream>>>(featb,wbf,bq,bk,bv,qbuf,kb,vbuf);
  k_fuse<<<dim3(2048),dim3(256),0,stream>>>(points,idxb,qbuf,kb,vbuf,Wd1,bd1,Wd2,bd2,stats,g1b,vab);
  k_finalizeP<<<dim3(2),dim3(64),0,stream>>>(stats,PG1,gg1,betag1,SG1_SC,SG1_SH);
  k_g<<<dim3(1024),dim3(512),0,stream>>>(g1b,wbf+49152,bg1,stats,SG1_SC,SG1_SH,g2b,PG2);
  k_finalizeP<<<dim3(2),dim3(64),0,stream>>>(stats,PG2,gg2,betag2,SG2_SC,SG2_SH);
  k_out<<<dim3(1024),dim3(512),0,stream>>>(g2b,wbf+65536,bg2,stats,SG2_SC,SG2_SH,vab,outp);
  (void)in_sizes; (void)n_in; (void)out_size; (void)ws_size;
}